// Round 3
// baseline (614.141 us; speedup 1.0000x reference)
//
#include <hip/hip_runtime.h>
#include <hip/hip_bf16.h>

#define N_NODES 100000
#define N_EDGES 1600000
#define IN_F 128
#define OUT_F 64

// ---------------------------------------------------------------------------
// K1: Wh = h @ W (fp32), fused f1 = Wh@a1, f2 = Wh@a2.
// Block = 256 = 4 waves; per wave: lane = out-feature (64), tid>>6 = node-in-tile.
// W (128x64 fp32, 32 KB) staged in LDS once per block; grid-stride over tiles.
// ---------------------------------------------------------------------------
__global__ __launch_bounds__(256) void k_gemm(
    const float* __restrict__ h,
    const float* __restrict__ W,
    const float* __restrict__ a1,
    const float* __restrict__ a2,
    float* __restrict__ Wh,
    float* __restrict__ f1,
    float* __restrict__ f2)
{
    __shared__ float Wl[IN_F * OUT_F];   // 32 KB
    __shared__ float hl[4][IN_F];        // 2 KB

    const int tid = threadIdx.x;
    for (int i = tid; i < IN_F * OUT_F; i += 256) Wl[i] = W[i];
    const int f  = tid & 63;
    const int nl = tid >> 6;
    const float a1f = a1[f];
    const float a2f = a2[f];

    const int ntiles = (N_NODES + 3) / 4;
    for (int tile = blockIdx.x; tile < ntiles; tile += gridDim.x) {
        const int base = tile * 4;
        __syncthreads();   // prev iter's hl reads done (covers Wl staging on iter 0)
        // 4 nodes x 128 feats = 512 floats, 256 threads, 2 each, coalesced
        #pragma unroll
        for (int rep = 0; rep < 2; rep++) {
            int i = tid + rep * 256;
            int n = i >> 7, k = i & 127;
            int gn = base + n;
            hl[n][k] = (gn < N_NODES) ? h[gn * IN_F + k] : 0.f;
        }
        __syncthreads();

        float acc = 0.f;
        #pragma unroll 8
        for (int k = 0; k < IN_F; k++)
            acc += hl[nl][k] * Wl[k * OUT_F + f];   // hl: wave-broadcast; Wl: 2-way (free)

        // wave-reduce f1/f2 across the 64 feature lanes
        float s1 = acc * a1f;
        float s2 = acc * a2f;
        #pragma unroll
        for (int m = 32; m >= 1; m >>= 1) {
            s1 += __shfl_xor(s1, m, 64);
            s2 += __shfl_xor(s2, m, 64);
        }

        const int node = base + nl;
        if (node < N_NODES) {
            Wh[node * OUT_F + f] = acc;
            if (f == 0) { f1[node] = s1; f2[node] = s2; }
        }
    }
}

// ---------------------------------------------------------------------------
// K2: e_exp = exp(leaky_relu(f1[row]+f2[col])); atomic esum[row] += e_exp.
// Global-max shift dropped: alpha is shift-invariant up to the 1e-10 eps term
// (relative perturbation ~1e-7 of per-row sums >= ~1e-2 — far below threshold).
// ---------------------------------------------------------------------------
__global__ __launch_bounds__(256) void k_edge_a(
    const int* __restrict__ ei,
    const float* __restrict__ f1,
    const float* __restrict__ f2,
    float* __restrict__ eexp,
    float* __restrict__ esum)
{
    int e = blockIdx.x * blockDim.x + threadIdx.x;
    const int stride = gridDim.x * blockDim.x;
    for (; e < N_EDGES; e += stride) {
        const int r = ei[e];
        const int c = ei[N_EDGES + e];
        float x = f1[r] + f2[c];
        x = (x >= 0.f) ? x : 0.2f * x;
        const float ee = __expf(x);
        eexp[e] = ee;
        atomicAdd(&esum[r], ee);
    }
}

// ---------------------------------------------------------------------------
// K3: one wave per edge; lane = feature. h_prime[row] += alpha * Wh[col]
// Gather Wh[col] (256 B contiguous / wave) + 64-lane contiguous atomicAdd.
// ---------------------------------------------------------------------------
__global__ __launch_bounds__(256) void k_edge_b(
    const int* __restrict__ ei,
    const float* __restrict__ eexp,
    const float* __restrict__ esum,
    const float* __restrict__ Wh,
    float* __restrict__ hp)
{
    const int lane = threadIdx.x & 63;
    int w = (blockIdx.x * blockDim.x + threadIdx.x) >> 6;
    const int nw = (gridDim.x * blockDim.x) >> 6;
    for (int e = w; e < N_EDGES; e += nw) {
        const int r = ei[e];
        const int c = ei[N_EDGES + e];
        const float alpha = eexp[e] / (esum[r] + 1e-10f);
        const float v = alpha * Wh[c * OUT_F + lane];
        atomicAdd(&hp[r * OUT_F + lane], v);
    }
}

// ---------------------------------------------------------------------------
// K4: out = elu(h_prime), fp32 store (reference output dtype is float32)
// ---------------------------------------------------------------------------
__global__ __launch_bounds__(256) void k_elu(
    const float* __restrict__ hp,
    float* __restrict__ out)
{
    int i = blockIdx.x * blockDim.x + threadIdx.x;
    const int stride = gridDim.x * blockDim.x;
    for (; i < N_NODES * OUT_F; i += stride) {
        const float x = hp[i];
        out[i] = (x > 0.f) ? x : expm1f(x);
    }
}

extern "C" void kernel_launch(void* const* d_in, const int* in_sizes, int n_in,
                              void* d_out, int out_size, void* d_ws, size_t ws_size,
                              hipStream_t stream) {
    const float* h  = (const float*)d_in[0];
    const float* W  = (const float*)d_in[1];
    const float* a1 = (const float*)d_in[2];
    const float* a2 = (const float*)d_in[3];
    const int* ei   = (const int*)d_in[4];
    float* out      = (float*)d_out;

    float* ws   = (float*)d_ws;
    float* Wh   = ws;                         // N*64
    float* f1   = Wh + N_NODES * OUT_F;       // N
    float* f2   = f1 + N_NODES;               // N
    float* esum = f2 + N_NODES;               // N
    float* eexp = esum + N_NODES;             // E
    float* hp   = eexp + N_EDGES;             // N*64   (total 58.8 MB)

    hipMemsetAsync(esum, 0, N_NODES * sizeof(float), stream);
    hipMemsetAsync(hp, 0, N_NODES * OUT_F * sizeof(float), stream);

    k_gemm  <<<2048, 256, 0, stream>>>(h, W, a1, a2, Wh, f1, f2);
    k_edge_a<<<4096, 256, 0, stream>>>(ei, f1, f2, eexp, esum);
    k_edge_b<<<16384, 256, 0, stream>>>(ei, eexp, esum, Wh, hp);
    k_elu   <<<4096, 256, 0, stream>>>(hp, out);
}

// Round 4
// 406.633 us; speedup vs baseline: 1.5103x; 1.5103x over previous
//
#include <hip/hip_runtime.h>
#include <hip/hip_bf16.h>

#define N_NODES 100000
#define N_EDGES 1600000
#define IN_F 128
#define OUT_F 64

#define SCAN_CHUNK 1024                       // elements per scan block (256 thr x 4)
#define N_SCAN_BLOCKS ((N_NODES + SCAN_CHUNK - 1) / SCAN_CHUNK)   // 98

// ---------------------------------------------------------------------------
// K1: Wh = h @ W (fp32), fused f1 = Wh@a1, f2 = Wh@a2.  (unchanged, proven)
// ---------------------------------------------------------------------------
__global__ __launch_bounds__(256) void k_gemm(
    const float* __restrict__ h,
    const float* __restrict__ W,
    const float* __restrict__ a1,
    const float* __restrict__ a2,
    float* __restrict__ Wh,
    float* __restrict__ f1,
    float* __restrict__ f2)
{
    __shared__ float Wl[IN_F * OUT_F];   // 32 KB
    __shared__ float hl[4][IN_F];        // 2 KB

    const int tid = threadIdx.x;
    for (int i = tid; i < IN_F * OUT_F; i += 256) Wl[i] = W[i];
    const int f  = tid & 63;
    const int nl = tid >> 6;
    const float a1f = a1[f];
    const float a2f = a2[f];

    const int ntiles = (N_NODES + 3) / 4;
    for (int tile = blockIdx.x; tile < ntiles; tile += gridDim.x) {
        const int base = tile * 4;
        __syncthreads();
        #pragma unroll
        for (int rep = 0; rep < 2; rep++) {
            int i = tid + rep * 256;
            int n = i >> 7, k = i & 127;
            int gn = base + n;
            hl[n][k] = (gn < N_NODES) ? h[gn * IN_F + k] : 0.f;
        }
        __syncthreads();

        float acc = 0.f;
        #pragma unroll 8
        for (int k = 0; k < IN_F; k++)
            acc += hl[nl][k] * Wl[k * OUT_F + f];

        float s1 = acc * a1f;
        float s2 = acc * a2f;
        #pragma unroll
        for (int m = 32; m >= 1; m >>= 1) {
            s1 += __shfl_xor(s1, m, 64);
            s2 += __shfl_xor(s2, m, 64);
        }

        const int node = base + nl;
        if (node < N_NODES) {
            Wh[node * OUT_F + f] = acc;
            if (f == 0) { f1[node] = s1; f2[node] = s2; }
        }
    }
}

// ---------------------------------------------------------------------------
// K2: degree histogram (deg must be pre-zeroed)
// ---------------------------------------------------------------------------
__global__ __launch_bounds__(256) void k_hist(const int* __restrict__ ei,
                                              int* __restrict__ deg)
{
    const int e = blockIdx.x * 256 + threadIdx.x;   // E % 256 == 0
    atomicAdd(&deg[ei[e]], 1);
}

// ---------------------------------------------------------------------------
// K3a: per-chunk totals (1024 deg values per block)
// ---------------------------------------------------------------------------
__global__ __launch_bounds__(256) void k_scanA(const int* __restrict__ deg,
                                               int* __restrict__ bsum)
{
    __shared__ int sd[256];
    const int t = threadIdx.x;
    const int i0 = blockIdx.x * SCAN_CHUNK + t * 4;
    int s = 0;
    #pragma unroll
    for (int k = 0; k < 4; k++) {
        int i = i0 + k;
        s += (i < N_NODES) ? deg[i] : 0;
    }
    sd[t] = s; __syncthreads();
    for (int off = 128; off >= 1; off >>= 1) {
        if (t < off) sd[t] += sd[t + off];
        __syncthreads();
    }
    if (t == 0) bsum[blockIdx.x] = sd[0];
}

// ---------------------------------------------------------------------------
// K3b: exclusive scan of the 98 chunk totals (single block, 128 threads)
// ---------------------------------------------------------------------------
__global__ __launch_bounds__(128) void k_scanB(const int* __restrict__ bsum,
                                               int* __restrict__ bbase)
{
    __shared__ int s[128];
    const int t = threadIdx.x;
    const int mine = (t < N_SCAN_BLOCKS) ? bsum[t] : 0;
    s[t] = mine; __syncthreads();
    for (int off = 1; off < 128; off <<= 1) {
        int v = (t >= off) ? s[t - off] : 0;
        __syncthreads();
        s[t] += v;
        __syncthreads();
    }
    if (t < N_SCAN_BLOCKS) bbase[t] = s[t] - mine;   // exclusive
}

// ---------------------------------------------------------------------------
// K3c: per-chunk exclusive scan + chunk offset -> base[] (row start offsets)
// ---------------------------------------------------------------------------
__global__ __launch_bounds__(256) void k_scanC(const int* __restrict__ deg,
                                               const int* __restrict__ bbase,
                                               int* __restrict__ base)
{
    __shared__ int ts[256];
    const int t = threadIdx.x;
    const int i0 = blockIdx.x * SCAN_CHUNK + t * 4;
    int v[4]; int s = 0;
    #pragma unroll
    for (int k = 0; k < 4; k++) {
        int i = i0 + k;
        v[k] = (i < N_NODES) ? deg[i] : 0;
        s += v[k];
    }
    ts[t] = s; __syncthreads();
    for (int off = 1; off < 256; off <<= 1) {        // inclusive Hillis-Steele
        int x = (t >= off) ? ts[t - off] : 0;
        __syncthreads();
        ts[t] += x;
        __syncthreads();
    }
    int excl = ts[t] - s + bbase[blockIdx.x];
    #pragma unroll
    for (int k = 0; k < 4; k++) {
        int i = i0 + k;
        if (i < N_NODES) base[i] = excl;
        excl += v[k];
    }
}

// ---------------------------------------------------------------------------
// K4: scatter edges into row-grouped order, packing {col, eexp} as 8B.
// Destructive cursor: pos = atomicAdd(&base[r],1). After this kernel,
// base[r] == row_end(r) and row_start(r) == base[r-1]  (0 for r==0).
// Global-max shift dropped: alpha is shift-invariant up to the 1e-10 eps.
// ---------------------------------------------------------------------------
__global__ __launch_bounds__(256) void k_scatter(
    const int* __restrict__ ei,
    const float* __restrict__ f1,
    const float* __restrict__ f2,
    int* __restrict__ base,
    uint2* __restrict__ pairs)
{
    const int e = blockIdx.x * 256 + threadIdx.x;   // E % 256 == 0
    const int r = ei[e];
    const int c = ei[N_EDGES + e];
    float x = f1[r] + f2[c];
    x = (x >= 0.f) ? x : 0.2f * x;
    const float ee = __expf(x);
    const int pos = atomicAdd(&base[r], 1);
    pairs[pos] = make_uint2((unsigned)c, __float_as_uint(ee));
}

// ---------------------------------------------------------------------------
// K5: one wave per node. acc = sum eexp*Wh[col], s = sum eexp;
// out = elu(acc/(s+eps)). No atomics; single coalesced row write.
// ---------------------------------------------------------------------------
__global__ __launch_bounds__(256) void k_agg(
    const int* __restrict__ base,
    const uint2* __restrict__ pairs,
    const float* __restrict__ Wh,
    float* __restrict__ out)
{
    const int wid  = (blockIdx.x * 256 + threadIdx.x) >> 6;   // node
    const int lane = threadIdx.x & 63;
    if (wid >= N_NODES) return;

    const int start = (wid > 0) ? base[wid - 1] : 0;
    const int end   = base[wid];

    float acc = 0.f, s = 0.f;
    int j = start;
    for (; j + 4 <= end; j += 4) {
        const uint2 p0 = pairs[j + 0];
        const uint2 p1 = pairs[j + 1];
        const uint2 p2 = pairs[j + 2];
        const uint2 p3 = pairs[j + 3];
        const float w0 = Wh[((int)p0.x << 6) + lane];
        const float w1 = Wh[((int)p1.x << 6) + lane];
        const float w2 = Wh[((int)p2.x << 6) + lane];
        const float w3 = Wh[((int)p3.x << 6) + lane];
        const float e0 = __uint_as_float(p0.y);
        const float e1 = __uint_as_float(p1.y);
        const float e2 = __uint_as_float(p2.y);
        const float e3 = __uint_as_float(p3.y);
        acc += e0 * w0 + e1 * w1 + e2 * w2 + e3 * w3;
        s   += e0 + e1 + e2 + e3;
    }
    for (; j < end; j++) {
        const uint2 p = pairs[j];
        const float ee = __uint_as_float(p.y);
        acc += ee * Wh[((int)p.x << 6) + lane];
        s   += ee;
    }

    const float r = acc / (s + 1e-10f);
    out[wid * OUT_F + lane] = (r > 0.f) ? r : expm1f(r);
}

extern "C" void kernel_launch(void* const* d_in, const int* in_sizes, int n_in,
                              void* d_out, int out_size, void* d_ws, size_t ws_size,
                              hipStream_t stream) {
    const float* h  = (const float*)d_in[0];
    const float* W  = (const float*)d_in[1];
    const float* a1 = (const float*)d_in[2];
    const float* a2 = (const float*)d_in[3];
    const int* ei   = (const int*)d_in[4];
    float* out      = (float*)d_out;

    float* ws    = (float*)d_ws;
    float* Wh    = ws;                          // N*64 floats
    float* f1    = Wh + N_NODES * OUT_F;        // N
    float* f2    = f1 + N_NODES;                // N
    int*   deg   = (int*)(f2 + N_NODES);        // N
    int*   base  = deg + N_NODES;               // N
    int*   bsum  = base + N_NODES;              // 128
    int*   bbase = bsum + 128;                  // 128
    uint2* pairs = (uint2*)(bbase + 128);       // E x 8B (offset is 8B-aligned)

    hipMemsetAsync(deg, 0, N_NODES * sizeof(int), stream);

    k_gemm   <<<2048, 256, 0, stream>>>(h, W, a1, a2, Wh, f1, f2);
    k_hist   <<<N_EDGES / 256, 256, 0, stream>>>(ei, deg);
    k_scanA  <<<N_SCAN_BLOCKS, 256, 0, stream>>>(deg, bsum);
    k_scanB  <<<1, 128, 0, stream>>>(bsum, bbase);
    k_scanC  <<<N_SCAN_BLOCKS, 256, 0, stream>>>(deg, bbase, base);
    k_scatter<<<N_EDGES / 256, 256, 0, stream>>>(ei, f1, f2, base, pairs);
    k_agg    <<<(N_NODES * 64 + 255) / 256, 256, 0, stream>>>(base, pairs, Wh, out);
}

// Round 5
// 333.683 us; speedup vs baseline: 1.8405x; 1.2186x over previous
//
#include <hip/hip_runtime.h>
#include <hip/hip_bf16.h>

#define N_NODES 100000
#define N_EDGES 1600000
#define IN_F 128
#define OUT_F 64

#define SCAN_CHUNK 1024
#define N_SCAN_BLOCKS ((N_NODES + SCAN_CHUNK - 1) / SCAN_CHUNK)   // 98

typedef __attribute__((ext_vector_type(8))) short short8;   // 8 bf16 = 4 VGPR
typedef __attribute__((ext_vector_type(4))) float f32x4;

#define LDS_PITCH 136   // 128 + 8 pad; row stride 272 B = 17*16 -> b128-aligned

__device__ __forceinline__ unsigned short f2bf(float x) {
    unsigned u = __float_as_uint(x);
    return (unsigned short)((u + 0x7FFFu + ((u >> 16) & 1u)) >> 16);  // RNE
}

// ---------------------------------------------------------------------------
// K0: wa1 = W @ a1, wa2 = W @ a2  (128-vectors; makes f1/f2 exact-fp32 later)
// ---------------------------------------------------------------------------
__global__ __launch_bounds__(128) void k_wa(
    const float* __restrict__ W,
    const float* __restrict__ a1,
    const float* __restrict__ a2,
    float* __restrict__ wa1,
    float* __restrict__ wa2)
{
    const int k = threadIdx.x;   // 0..127
    float s1 = 0.f, s2 = 0.f;
    #pragma unroll 8
    for (int f = 0; f < OUT_F; f++) {
        const float w = W[k * OUT_F + f];
        s1 += w * a1[f];
        s2 += w * a2[f];
    }
    wa1[k] = s1;
    wa2[k] = s2;
}

// ---------------------------------------------------------------------------
// K1: Wh = h @ W via bf16 MFMA (fp32 accum); f1/f2 fused in fp32 from wa1/wa2.
// Block 256 = 4 waves. Tile = 16 nodes. Wave w computes cols [16w,16w+16).
// W^T staged once per block in LDS (bf16); B-fragments hoisted to registers.
// ---------------------------------------------------------------------------
__global__ __launch_bounds__(256) void k_gemm(
    const float* __restrict__ h,
    const float* __restrict__ W,
    const float* __restrict__ wa1,
    const float* __restrict__ wa2,
    float* __restrict__ Wh,
    float* __restrict__ f1,
    float* __restrict__ f2)
{
    __shared__ unsigned short Wt[OUT_F * LDS_PITCH];  // W^T bf16: [n][k], 17408 B
    __shared__ unsigned short Al[16 * LDS_PITCH];     // A tile bf16: [m][k], 4352 B

    const int tid  = threadIdx.x;
    const int lane = tid & 63;
    const int wav  = tid >> 6;        // 0..3 -> col slice
    const int quad = lane >> 4;       // 0..3
    const int nl   = lane & 15;

    // stage W^T (bf16) once
    for (int i = tid; i < IN_F * OUT_F; i += 256) {
        const int k = i >> 6, f = i & 63;
        Wt[f * LDS_PITCH + k] = f2bf(W[i]);
    }
    __syncthreads();

    // hoist loop-invariant B fragments: B[k = ch*32 + quad*8 + j][n = 16*wav + nl]
    short8 bfrag[4];
    #pragma unroll
    for (int ch = 0; ch < 4; ch++) {
        const int row = wav * 16 + nl;
        const int kb  = ch * 32 + quad * 8;
        bfrag[ch] = *(const short8*)&Wt[row * LDS_PITCH + kb];
    }

    // staging/f1f2 thread mapping: row = tid>>4 (0..15), chunk c = tid&15 (8 floats)
    const int srow = tid >> 4;
    const int sc   = tid & 15;
    float w1r[8], w2r[8];
    #pragma unroll
    for (int j = 0; j < 8; j++) { w1r[j] = wa1[sc * 8 + j]; w2r[j] = wa2[sc * 8 + j]; }

    const int ntiles = N_NODES / 16;   // 6250, exact
    for (int tile = blockIdx.x; tile < ntiles; tile += gridDim.x) {
        const int base = tile * 16;

        __syncthreads();   // protect Al from previous iteration's ds_reads

        // load 16x128 fp32 (coalesced float4), fuse f1/f2, convert+store bf16
        const float4 v0 = *(const float4*)&h[(base + srow) * IN_F + sc * 8];
        const float4 v1 = *(const float4*)&h[(base + srow) * IN_F + sc * 8 + 4];
        float p1 = v0.x * w1r[0] + v0.y * w1r[1] + v0.z * w1r[2] + v0.w * w1r[3]
                 + v1.x * w1r[4] + v1.y * w1r[5] + v1.z * w1r[6] + v1.w * w1r[7];
        float p2 = v0.x * w2r[0] + v0.y * w2r[1] + v0.z * w2r[2] + v0.w * w2r[3]
                 + v1.x * w2r[4] + v1.y * w2r[5] + v1.z * w2r[6] + v1.w * w2r[7];
        #pragma unroll
        for (int m = 8; m >= 1; m >>= 1) {   // reduce over 16 chunk-lanes
            p1 += __shfl_xor(p1, m, 64);
            p2 += __shfl_xor(p2, m, 64);
        }
        if (sc == 0) { f1[base + srow] = p1; f2[base + srow] = p2; }

        uint4 packed;
        packed.x = (unsigned)f2bf(v0.x) | ((unsigned)f2bf(v0.y) << 16);
        packed.y = (unsigned)f2bf(v0.z) | ((unsigned)f2bf(v0.w) << 16);
        packed.z = (unsigned)f2bf(v1.x) | ((unsigned)f2bf(v1.y) << 16);
        packed.w = (unsigned)f2bf(v1.z) | ((unsigned)f2bf(v1.w) << 16);
        *(uint4*)&Al[srow * LDS_PITCH + sc * 8] = packed;

        __syncthreads();

        // MFMA: A[m = nl][k = ch*32 + quad*8 + j]
        f32x4 acc = {0.f, 0.f, 0.f, 0.f};
        #pragma unroll
        for (int ch = 0; ch < 4; ch++) {
            const short8 afrag = *(const short8*)&Al[nl * LDS_PITCH + ch * 32 + quad * 8];
            acc = __builtin_amdgcn_mfma_f32_16x16x32_bf16(afrag, bfrag[ch], acc, 0, 0, 0);
        }

        // C/D layout: col = lane&15 (n), row = quad*4 + reg (m)
        const int col = wav * 16 + nl;
        #pragma unroll
        for (int r = 0; r < 4; r++)
            Wh[(base + quad * 4 + r) * OUT_F + col] = acc[r];
    }
}

// ---------------------------------------------------------------------------
// K2: degree histogram (deg pre-zeroed)
// ---------------------------------------------------------------------------
__global__ __launch_bounds__(256) void k_hist(const int* __restrict__ ei,
                                              int* __restrict__ deg)
{
    const int e = blockIdx.x * 256 + threadIdx.x;
    atomicAdd(&deg[ei[e]], 1);
}

// ---------------------------------------------------------------------------
// K3a/b/c: block scan of degrees -> base[] row offsets
// ---------------------------------------------------------------------------
__global__ __launch_bounds__(256) void k_scanA(const int* __restrict__ deg,
                                               int* __restrict__ bsum)
{
    __shared__ int sd[256];
    const int t = threadIdx.x;
    const int i0 = blockIdx.x * SCAN_CHUNK + t * 4;
    int s = 0;
    #pragma unroll
    for (int k = 0; k < 4; k++) {
        int i = i0 + k;
        s += (i < N_NODES) ? deg[i] : 0;
    }
    sd[t] = s; __syncthreads();
    for (int off = 128; off >= 1; off >>= 1) {
        if (t < off) sd[t] += sd[t + off];
        __syncthreads();
    }
    if (t == 0) bsum[blockIdx.x] = sd[0];
}

__global__ __launch_bounds__(128) void k_scanB(const int* __restrict__ bsum,
                                               int* __restrict__ bbase)
{
    __shared__ int s[128];
    const int t = threadIdx.x;
    const int mine = (t < N_SCAN_BLOCKS) ? bsum[t] : 0;
    s[t] = mine; __syncthreads();
    for (int off = 1; off < 128; off <<= 1) {
        int v = (t >= off) ? s[t - off] : 0;
        __syncthreads();
        s[t] += v;
        __syncthreads();
    }
    if (t < N_SCAN_BLOCKS) bbase[t] = s[t] - mine;
}

__global__ __launch_bounds__(256) void k_scanC(const int* __restrict__ deg,
                                               const int* __restrict__ bbase,
                                               int* __restrict__ base)
{
    __shared__ int ts[256];
    const int t = threadIdx.x;
    const int i0 = blockIdx.x * SCAN_CHUNK + t * 4;
    int v[4]; int s = 0;
    #pragma unroll
    for (int k = 0; k < 4; k++) {
        int i = i0 + k;
        v[k] = (i < N_NODES) ? deg[i] : 0;
        s += v[k];
    }
    ts[t] = s; __syncthreads();
    for (int off = 1; off < 256; off <<= 1) {
        int x = (t >= off) ? ts[t - off] : 0;
        __syncthreads();
        ts[t] += x;
        __syncthreads();
    }
    int excl = ts[t] - s + bbase[blockIdx.x];
    #pragma unroll
    for (int k = 0; k < 4; k++) {
        int i = i0 + k;
        if (i < N_NODES) base[i] = excl;
        excl += v[k];
    }
}

// ---------------------------------------------------------------------------
// K4: scatter edges row-grouped, packing {col, eexp}. Destructive cursor:
// after this kernel base[r] == row_end(r); row_start(r) == base[r-1].
// ---------------------------------------------------------------------------
__global__ __launch_bounds__(256) void k_scatter(
    const int* __restrict__ ei,
    const float* __restrict__ f1,
    const float* __restrict__ f2,
    int* __restrict__ base,
    uint2* __restrict__ pairs)
{
    const int e = blockIdx.x * 256 + threadIdx.x;
    const int r = ei[e];
    const int c = ei[N_EDGES + e];
    float x = f1[r] + f2[c];
    x = (x >= 0.f) ? x : 0.2f * x;
    const float ee = __expf(x);
    const int pos = atomicAdd(&base[r], 1);
    pairs[pos] = make_uint2((unsigned)c, __float_as_uint(ee));
}

// ---------------------------------------------------------------------------
// K5: one wave per node; out = elu( (sum eexp*Wh[col]) / (sum eexp + eps) )
// ---------------------------------------------------------------------------
__global__ __launch_bounds__(256) void k_agg(
    const int* __restrict__ base,
    const uint2* __restrict__ pairs,
    const float* __restrict__ Wh,
    float* __restrict__ out)
{
    const int wid  = (blockIdx.x * 256 + threadIdx.x) >> 6;
    const int lane = threadIdx.x & 63;
    if (wid >= N_NODES) return;

    const int start = (wid > 0) ? base[wid - 1] : 0;
    const int end   = base[wid];

    float acc = 0.f, s = 0.f;
    int j = start;
    for (; j + 4 <= end; j += 4) {
        const uint2 p0 = pairs[j + 0];
        const uint2 p1 = pairs[j + 1];
        const uint2 p2 = pairs[j + 2];
        const uint2 p3 = pairs[j + 3];
        const float w0 = Wh[((int)p0.x << 6) + lane];
        const float w1 = Wh[((int)p1.x << 6) + lane];
        const float w2 = Wh[((int)p2.x << 6) + lane];
        const float w3 = Wh[((int)p3.x << 6) + lane];
        const float e0 = __uint_as_float(p0.y);
        const float e1 = __uint_as_float(p1.y);
        const float e2 = __uint_as_float(p2.y);
        const float e3 = __uint_as_float(p3.y);
        acc += e0 * w0 + e1 * w1 + e2 * w2 + e3 * w3;
        s   += e0 + e1 + e2 + e3;
    }
    for (; j < end; j++) {
        const uint2 p = pairs[j];
        const float ee = __uint_as_float(p.y);
        acc += ee * Wh[((int)p.x << 6) + lane];
        s   += ee;
    }

    const float r = acc / (s + 1e-10f);
    out[wid * OUT_F + lane] = (r > 0.f) ? r : expm1f(r);
}

extern "C" void kernel_launch(void* const* d_in, const int* in_sizes, int n_in,
                              void* d_out, int out_size, void* d_ws, size_t ws_size,
                              hipStream_t stream) {
    const float* h  = (const float*)d_in[0];
    const float* W  = (const float*)d_in[1];
    const float* a1 = (const float*)d_in[2];
    const float* a2 = (const float*)d_in[3];
    const int* ei   = (const int*)d_in[4];
    float* out      = (float*)d_out;

    float* ws    = (float*)d_ws;
    float* Wh    = ws;                          // N*64
    float* f1    = Wh + N_NODES * OUT_F;        // N
    float* f2    = f1 + N_NODES;                // N
    int*   deg   = (int*)(f2 + N_NODES);        // N
    int*   base  = deg + N_NODES;               // N
    int*   bsum  = base + N_NODES;              // 128
    int*   bbase = bsum + 128;                  // 128
    float* wa1   = (float*)(bbase + 128);       // 128
    float* wa2   = wa1 + 128;                   // 128
    uint2* pairs = (uint2*)(wa2 + 128);         // E x 8B (8B-aligned offset)

    hipMemsetAsync(deg, 0, N_NODES * sizeof(int), stream);

    k_wa     <<<1, 128, 0, stream>>>(W, a1, a2, wa1, wa2);
    k_gemm   <<<1250, 256, 0, stream>>>(h, W, wa1, wa2, Wh, f1, f2);
    k_hist   <<<N_EDGES / 256, 256, 0, stream>>>(ei, deg);
    k_scanA  <<<N_SCAN_BLOCKS, 256, 0, stream>>>(deg, bsum);
    k_scanB  <<<1, 128, 0, stream>>>(bsum, bbase);
    k_scanC  <<<N_SCAN_BLOCKS, 256, 0, stream>>>(deg, bbase, base);
    k_scatter<<<N_EDGES / 256, 256, 0, stream>>>(ei, f1, f2, base, pairs);
    k_agg    <<<(N_NODES * 64 + 255) / 256, 256, 0, stream>>>(base, pairs, Wh, out);
}